// Round 8
// baseline (8612.750 us; speedup 1.0000x reference)
//
#include <hip/hip_runtime.h>

#define T_TOTAL 131072
#define NH1 64
#define NH2 32
#define NS 64
#define PF_B 8            // scan prefetch depth, in 12-step blocks

// ---------------------------------------------------------------------------
// Kernel 1: MLP priors.  llr[t][s] = -( relu(relu(x*W1+b1)@W2+b2)@W3+b3 )[s]
// UNCHANGED since round 1 (absmax 0.0) — do not perturb arithmetic.
// ---------------------------------------------------------------------------
__global__ __launch_bounds__(256) void mlp_kernel(
    const float* __restrict__ rx, const float* __restrict__ W1,
    const float* __restrict__ b1, const float* __restrict__ W2,
    const float* __restrict__ b2, const float* __restrict__ W3,
    const float* __restrict__ b3, float* __restrict__ llr, int n) {
#pragma clang fp contract(on)
  __shared__ float sW2[NH1 * NH2], sW3[NH2 * NS];
  __shared__ float sW1[NH1], sb1[NH1], sb2[NH2], sb3[NS];
  int tid = threadIdx.x;
  for (int i = tid; i < NH1 * NH2; i += 256) sW2[i] = W2[i];
  for (int i = tid; i < NH2 * NS; i += 256) sW3[i] = W3[i];
  if (tid < NH1) { sW1[tid] = W1[tid]; sb1[tid] = b1[tid]; }
  if (tid < NH2) sb2[tid] = b2[tid];
  if (tid < NS)  sb3[tid] = b3[tid];
  __syncthreads();

  int t = blockIdx.x * 256 + tid;
  if (t >= n) return;
  float x = rx[t];

  float h1[NH1];
#pragma unroll
  for (int j = 0; j < NH1; ++j) {
    float p = x * sW1[j];
    float s = p + sb1[j];
    h1[j] = fmaxf(s, 0.0f);
  }
  float h2[NH2];
#pragma unroll
  for (int k = 0; k < NH2; ++k) {
    float acc = 0.0f;
#pragma unroll
    for (int j = 0; j < NH1; ++j) acc += h1[j] * sW2[j * NH2 + k];
    float s = acc + sb2[k];
    h2[k] = fmaxf(s, 0.0f);
  }
#pragma unroll
  for (int s_ = 0; s_ < NS; ++s_) {
    float acc = 0.0f;
#pragma unroll
    for (int k = 0; k < NH2; ++k) acc += h2[k] * sW3[k * NS + s_];
    float o = acc + sb3[s_];
    llr[(size_t)t * NS + s_] = -o;
  }
}

// ---------------------------------------------------------------------------
// Kernel 2: pack llr into per-lane float4 blocks for the scan (r6/r7 verified):
//   sllr2[b*768 + q*256 + l*4 + j] = llrnat[(12b+4q+j)*64 + perm_{(4q+j)%6}(l)]
// ---------------------------------------------------------------------------
__global__ __launch_bounds__(256) void pack_kernel(
    const float* __restrict__ llrnat, float4* __restrict__ sllr2,
    int nsteps, int npblocks) {
  int id = blockIdx.x * 256 + threadIdx.x;
  if (id >= npblocks * 192) return;
  int b = id / 192, rq = id % 192, q = rq >> 6, l = rq & 63;
  static const int SH[6][6] = {
    {5,4,3,0,1,2}, {4,3,2,5,0,1}, {3,2,1,4,5,0},
    {2,1,0,3,4,5}, {1,0,5,2,3,4}, {0,5,4,1,2,3},
  };
  float v[4];
#pragma unroll
  for (int j = 0; j < 4; ++j) {
    int step = 12 * b + 4 * q + j;
    if (step >= nsteps) step = nsteps - 1;   // clamped pad (values unused)
    const int* s = SH[(4 * q + j) % 6];
    int idx = ((l & 1) << s[0]) | (((l >> 1) & 1) << s[1]) | (((l >> 2) & 1) << s[2])
            | (((l >> 3) & 1) << s[3]) | (((l >> 4) & 1) << s[4]) | (((l >> 5) & 1) << s[5]);
    v[j] = llrnat[(size_t)step * 64 + idx];
  }
  sllr2[(size_t)b * 192 + q * 64 + l] = make_float4(v[0], v[1], v[2], v[3]);
}

// ---------------------------------------------------------------------------
// Fused route+min helpers (r7-verified, absmax 0.0).  s_nop 1 = the 2 wait
// states for the VALU->DPP hazard (compiler can't see inside asm).
// ---------------------------------------------------------------------------
#define DPPF(x, c) __builtin_amdgcn_mov_dpp((x), (c), 0xF, 0xF, true)
__device__ __forceinline__ float amin1(float t) {
  float o; asm("s_nop 1\n\tv_min_f32_dpp %0, %1, %1 quad_perm:[1,0,3,2] row_mask:0xf bank_mask:0xf"
               : "=v"(o) : "v"(t)); return o;
}
__device__ __forceinline__ float amin2(float t) {
  float o; asm("s_nop 1\n\tv_min_f32_dpp %0, %1, %1 quad_perm:[2,3,0,1] row_mask:0xf bank_mask:0xf"
               : "=v"(o) : "v"(t)); return o;
}
__device__ __forceinline__ float amin8(float t) {
  float o; asm("s_nop 1\n\tv_min_f32_dpp %0, %1, %1 row_ror:8 row_mask:0xf bank_mask:0xf"
               : "=v"(o) : "v"(t)); return o;
}
__device__ __forceinline__ float amin4(float t) {
  float u = __int_as_float(DPPF(__float_as_int(t), 0x141));   // t[l^7]
  float o; asm("s_nop 1\n\tv_min_f32_dpp %0, %1, %2 quad_perm:[3,2,1,0] row_mask:0xf bank_mask:0xf"
               : "=v"(o) : "v"(u), "v"(t)); return o;          // min(t[l^4], t)
}

typedef unsigned int uint2v __attribute__((ext_vector_type(2)));
#if __has_builtin(__builtin_amdgcn_permlane16_swap) && __has_builtin(__builtin_amdgcn_permlane32_swap)
__device__ __forceinline__ float minx16(float v) {
  uint2v pr = __builtin_amdgcn_permlane16_swap(__float_as_uint(v), __float_as_uint(v), false, false);
  return fminf(__uint_as_float(pr[0]), __uint_as_float(pr[1]));
}
__device__ __forceinline__ float minx32(float v) {
  uint2v pr = __builtin_amdgcn_permlane32_swap(__float_as_uint(v), __float_as_uint(v), false, false);
  return fminf(__uint_as_float(pr[0]), __uint_as_float(pr[1]));
}
#else
__device__ __forceinline__ float minx16(float v) {
  int a = (((int)threadIdx.x ^ 16) & 63) << 2;
  return fminf(v, __int_as_float(__builtin_amdgcn_ds_bpermute(a, __float_as_int(v))));
}
__device__ __forceinline__ float minx32(float v) {
  int a = (((int)threadIdx.x ^ 32) & 63) << 2;
  return fminf(v, __int_as_float(__builtin_amdgcn_ds_bpermute(a, __float_as_int(v))));
}
#endif

#if __has_builtin(__builtin_amdgcn_sched_barrier)
#define SCHED_FENCE() __builtin_amdgcn_sched_barrier(0)
#else
#define SCHED_FENCE()
#endif
// Pin a loaded float4 at its issue site and keep it opaque in a VGPR until
// consumed (blocks the compiler's load-sinking/forwarding that collapsed the
// software pipeline in rounds 5-7 — VGPR_Count 44 proved Q[][] never stayed
// live across the backedge).
#define OPQ4(v) asm volatile("" : "+v"((v).x), "+v"((v).y), "+v"((v).z), "+v"((v).w))

// ---------------------------------------------------------------------------
// Kernel 3: sequential Viterbi recurrence.  Arithmetic (operands + op order)
// IDENTICAL to rounds 6/7 (absmax 0.0): per step { t = prob + r ; prob =
// pair-min over mask m }.  Mask schedule per 12-step block:
//   group0: 8,16,32,4 | group1: 2,1,8,16 | group2: 32,4,2,1
// Boundary row stored once per block (pre-update, phase-0 layout).
// ---------------------------------------------------------------------------
__global__ __launch_bounds__(64) void scan_kernel(
    const float4* __restrict__ sllr2, float* __restrict__ trajB,
    float* __restrict__ state, int nblocks, int rem, int first) {
  const int l = threadIdx.x;
  float prob = first ? 0.0f : state[l];
  const float4* sp = sllr2 + l;        // lane-stride 16B; block stride 192 f4
  float* tb = trajB + l;

#define GROUP(qv, M1, M2, M3, M4)                   \
  do { float t_;                                    \
    t_ = prob + (qv).x; prob = M1(t_);              \
    t_ = prob + (qv).y; prob = M2(t_);              \
    t_ = prob + (qv).z; prob = M3(t_);              \
    t_ = prob + (qv).w; prob = M4(t_);              \
  } while (0)

#define BLKBODY(q0, q1, q2, BIDX)                   \
  do { tb[(size_t)(BIDX) * 64] = prob;              \
    GROUP(q0, amin8,  minx16, minx32, amin4);       \
    GROUP(q1, amin2,  amin1,  amin8,  minx16);      \
    GROUP(q2, minx32, amin4,  amin2,  amin1);       \
  } while (0)

  const int Bm = (nblocks / PF_B) * PF_B;
  float4 Q[PF_B][3];
#pragma unroll
  for (int s = 0; s < PF_B; ++s) {
#pragma unroll
    for (int q = 0; q < 3; ++q) { Q[s][q] = sp[(size_t)s * 192 + q * 64]; OPQ4(Q[s][q]); }
  }

  for (int B = 0; B < Bm; B += PF_B) {
#pragma unroll
    for (int s = 0; s < PF_B; ++s) {
      float4 q0 = Q[s][0], q1 = Q[s][1], q2 = Q[s][2];
      {  // refill slot s with block B+s+PF_B (pads allocated past the end)
        const float4* nb = sp + (size_t)(B + s + PF_B) * 192;
        Q[s][0] = nb[0];   OPQ4(Q[s][0]);
        Q[s][1] = nb[64];  OPQ4(Q[s][1]);
        Q[s][2] = nb[128]; OPQ4(Q[s][2]);
      }
      BLKBODY(q0, q1, q2, B + s);
      SCHED_FENCE();
    }
  }
  for (int B2 = Bm; B2 < nblocks; ++B2) {   // leftover blocks, direct loads
    const float4* nb = sp + (size_t)B2 * 192;
    float4 q0 = nb[0], q1 = nb[64], q2 = nb[128];
    BLKBODY(q0, q1, q2, B2);
  }
  if (rem > 0) {  // tail groups (<3): store boundary, run phase0 (+phase1)
    const float4* nb = sp + (size_t)nblocks * 192;
    tb[(size_t)nblocks * 64] = prob;
    float4 q0 = nb[0];
    GROUP(q0, amin8, minx16, minx32, amin4);
    if (rem > 1) {
      float4 q1 = nb[64];
      GROUP(q1, amin2, amin1, amin8, minx16);
    }
  }
  state[l] = prob;
#undef GROUP
#undef BLKBODY
}

// ---------------------------------------------------------------------------
// Kernel 4: per-t bit.  Un-permute block-boundary row with sigma0^-1 (r5-r7
// verified formula), rebuild r = t%12 local trellis steps (exact reference op
// order), strict-< argmin parity (first-index tie-break).
// ---------------------------------------------------------------------------
__global__ __launch_bounds__(256) void bits_kernel(
    const float* __restrict__ trajB, const float* __restrict__ llrnat,
    float* __restrict__ out, int n) {
  int t = blockIdx.x * 256 + threadIdx.x;
  if (t >= n) return;
  int bk = t / 12, r = t % 12;
  const float* row64 = trajB + (size_t)bk * 64;
  float cur[32];
#pragma unroll
  for (int j = 0; j < 32; ++j) {
    int j0 = j & 1, j1 = (j >> 1) & 1, j2 = (j >> 2) & 1, j3 = (j >> 3) & 1, j4 = (j >> 4) & 1;
    cur[j] = row64[8 * j0 + 16 * j1 + 32 * j2 + 4 * j3 + 2 * j4];
  }
  for (int q = 0; q < r; ++q) {
    const float* L = llrnat + (size_t)(12 * bk + q) * 64;
    float nw[32];
#pragma unroll
    for (int j = 0; j < 32; ++j) {
      nw[j] = fminf(cur[(2 * j) & 31] + L[2 * j], cur[(2 * j + 1) & 31] + L[2 * j + 1]);
    }
#pragma unroll
    for (int j = 0; j < 32; ++j) cur[j] = nw[j];
  }
  float best = cur[0]; int bi = 0;
#pragma unroll
  for (int i = 1; i < 32; ++i) {
    if (cur[i] < best) { best = cur[i]; bi = i; }
  }
  out[t] = (float)(bi & 1);
}

// ---------------------------------------------------------------------------
extern "C" void kernel_launch(void* const* d_in, const int* in_sizes, int n_in,
                              void* d_out, int out_size, void* d_ws, size_t ws_size,
                              hipStream_t stream) {
  const float* rx = (const float*)d_in[0];
  const float* W1 = (const float*)d_in[1];
  const float* b1 = (const float*)d_in[2];
  const float* W2 = (const float*)d_in[3];
  const float* b2 = (const float*)d_in[4];
  const float* W3 = (const float*)d_in[5];
  const float* b3 = (const float*)d_in[6];
  float* out = (float*)d_out;

  // ws: llrnat(CH*64) + sllr2((ceil(CH/12)+PF_B+1)*768) + trajB((CH/12+2)*64) + state
#define NEED(c) ((size_t)(c) * 64 * 4 \
               + ((size_t)(((c) + 11) / 12) + PF_B + 1) * 768 * 4 \
               + ((size_t)(c) / 12 + 2) * 64 * 4 + 1024)
  int CH = -1;
  if (NEED(T_TOTAL) <= ws_size) CH = T_TOTAL;
  if (CH < 0) {
    for (int m = T_TOTAL / 3072; m >= 1; --m) {
      int c = 3072 * m;
      if (NEED(c) <= ws_size) { CH = c; break; }
    }
  }
  if (CH < 0) CH = 3072;
#undef NEED

  float*  llrnat = (float*)d_ws;
  float4* sllr2  = (float4*)(llrnat + (size_t)CH * 64);
  float*  trajB  = (float*)(sllr2 + ((size_t)((CH + 11) / 12) + PF_B + 1) * 192);
  float*  state  = trajB + ((size_t)CH / 12 + 2) * 64;

  for (int t0 = 0; t0 < T_TOTAL; t0 += CH) {
    int c = (T_TOTAL - t0 < CH) ? (T_TOTAL - t0) : CH;  // multiple of 1024
    int npb = (c + 11) / 12;
    int nblocks = c / 4 / 3;            // whole 12-step blocks
    int rem = c / 4 - 3 * nblocks;      // leftover 4-step groups (0..2)
    mlp_kernel <<<c / 256, 256, 0, stream>>>(rx + t0, W1, b1, W2, b2, W3, b3, llrnat, c);
    pack_kernel<<<(npb * 192 + 255) / 256, 256, 0, stream>>>(llrnat, sllr2, c, npb);
    scan_kernel<<<1, 64, 0, stream>>>(sllr2, trajB, state, nblocks, rem, (t0 == 0) ? 1 : 0);
    bits_kernel<<<c / 256, 256, 0, stream>>>(trajB, llrnat, out + t0, c);
  }
}

// Round 9
// 1714.234 us; speedup vs baseline: 5.0243x; 5.0243x over previous
//
#include <hip/hip_runtime.h>

#define T_TOTAL 131072
#define NH1 64
#define NH2 32
#define NS 64
#define H 8               // blocks per ring half (LDS ring = 2*H*3KB = 48KB)

// ---------------------------------------------------------------------------
// Kernel 1: MLP priors.  UNCHANGED since round 1 (absmax 0.0).
// ---------------------------------------------------------------------------
__global__ __launch_bounds__(256) void mlp_kernel(
    const float* __restrict__ rx, const float* __restrict__ W1,
    const float* __restrict__ b1, const float* __restrict__ W2,
    const float* __restrict__ b2, const float* __restrict__ W3,
    const float* __restrict__ b3, float* __restrict__ llr, int n) {
#pragma clang fp contract(on)
  __shared__ float sW2[NH1 * NH2], sW3[NH2 * NS];
  __shared__ float sW1[NH1], sb1[NH1], sb2[NH2], sb3[NS];
  int tid = threadIdx.x;
  for (int i = tid; i < NH1 * NH2; i += 256) sW2[i] = W2[i];
  for (int i = tid; i < NH2 * NS; i += 256) sW3[i] = W3[i];
  if (tid < NH1) { sW1[tid] = W1[tid]; sb1[tid] = b1[tid]; }
  if (tid < NH2) sb2[tid] = b2[tid];
  if (tid < NS)  sb3[tid] = b3[tid];
  __syncthreads();

  int t = blockIdx.x * 256 + tid;
  if (t >= n) return;
  float x = rx[t];

  float h1[NH1];
#pragma unroll
  for (int j = 0; j < NH1; ++j) {
    float p = x * sW1[j];
    float s = p + sb1[j];
    h1[j] = fmaxf(s, 0.0f);
  }
  float h2[NH2];
#pragma unroll
  for (int k = 0; k < NH2; ++k) {
    float acc = 0.0f;
#pragma unroll
    for (int j = 0; j < NH1; ++j) acc += h1[j] * sW2[j * NH2 + k];
    float s = acc + sb2[k];
    h2[k] = fmaxf(s, 0.0f);
  }
#pragma unroll
  for (int s_ = 0; s_ < NS; ++s_) {
    float acc = 0.0f;
#pragma unroll
    for (int k = 0; k < NH2; ++k) acc += h2[k] * sW3[k * NS + s_];
    float o = acc + sb3[s_];
    llr[(size_t)t * NS + s_] = -o;
  }
}

// ---------------------------------------------------------------------------
// Kernel 2: pack llr into per-lane float4 blocks (r6/r7 verified layout):
//   sllr2[b*768 + q*256 + l*4 + j] = llrnat[(12b+4q+j)*64 + perm_{(4q+j)%6}(l)]
// ---------------------------------------------------------------------------
__global__ __launch_bounds__(256) void pack_kernel(
    const float* __restrict__ llrnat, float4* __restrict__ sllr2,
    int nsteps, int npblocks) {
  int id = blockIdx.x * 256 + threadIdx.x;
  if (id >= npblocks * 192) return;
  int b = id / 192, rq = id % 192, q = rq >> 6, l = rq & 63;
  static const int SH[6][6] = {
    {5,4,3,0,1,2}, {4,3,2,5,0,1}, {3,2,1,4,5,0},
    {2,1,0,3,4,5}, {1,0,5,2,3,4}, {0,5,4,1,2,3},
  };
  float v[4];
#pragma unroll
  for (int j = 0; j < 4; ++j) {
    int step = 12 * b + 4 * q + j;
    if (step >= nsteps) step = nsteps - 1;   // clamped pad (values unused)
    const int* s = SH[(4 * q + j) % 6];
    int idx = ((l & 1) << s[0]) | (((l >> 1) & 1) << s[1]) | (((l >> 2) & 1) << s[2])
            | (((l >> 3) & 1) << s[3]) | (((l >> 4) & 1) << s[4]) | (((l >> 5) & 1) << s[5]);
    v[j] = llrnat[(size_t)step * 64 + idx];
  }
  sllr2[(size_t)b * 192 + q * 64 + l] = make_float4(v[0], v[1], v[2], v[3]);
}

// ---------------------------------------------------------------------------
// Fused route+min helpers (r7-verified, absmax 0.0).
// ---------------------------------------------------------------------------
#define DPPF(x, c) __builtin_amdgcn_mov_dpp((x), (c), 0xF, 0xF, true)
__device__ __forceinline__ float amin1(float t) {
  float o; asm("s_nop 1\n\tv_min_f32_dpp %0, %1, %1 quad_perm:[1,0,3,2] row_mask:0xf bank_mask:0xf"
               : "=v"(o) : "v"(t)); return o;
}
__device__ __forceinline__ float amin2(float t) {
  float o; asm("s_nop 1\n\tv_min_f32_dpp %0, %1, %1 quad_perm:[2,3,0,1] row_mask:0xf bank_mask:0xf"
               : "=v"(o) : "v"(t)); return o;
}
__device__ __forceinline__ float amin8(float t) {
  float o; asm("s_nop 1\n\tv_min_f32_dpp %0, %1, %1 row_ror:8 row_mask:0xf bank_mask:0xf"
               : "=v"(o) : "v"(t)); return o;
}
__device__ __forceinline__ float amin4(float t) {
  float u = __int_as_float(DPPF(__float_as_int(t), 0x141));   // t[l^7]
  float o; asm("s_nop 1\n\tv_min_f32_dpp %0, %1, %2 quad_perm:[3,2,1,0] row_mask:0xf bank_mask:0xf"
               : "=v"(o) : "v"(u), "v"(t)); return o;          // min(t[l^4], t)
}

typedef unsigned int uint2v __attribute__((ext_vector_type(2)));
#if __has_builtin(__builtin_amdgcn_permlane16_swap) && __has_builtin(__builtin_amdgcn_permlane32_swap)
__device__ __forceinline__ float minx16(float v) {
  uint2v pr = __builtin_amdgcn_permlane16_swap(__float_as_uint(v), __float_as_uint(v), false, false);
  return fminf(__uint_as_float(pr[0]), __uint_as_float(pr[1]));
}
__device__ __forceinline__ float minx32(float v) {
  uint2v pr = __builtin_amdgcn_permlane32_swap(__float_as_uint(v), __float_as_uint(v), false, false);
  return fminf(__uint_as_float(pr[0]), __uint_as_float(pr[1]));
}
#else
__device__ __forceinline__ float minx16(float v) {
  int a = (((int)threadIdx.x ^ 16) & 63) << 2;
  return fminf(v, __int_as_float(__builtin_amdgcn_ds_bpermute(a, __float_as_int(v))));
}
__device__ __forceinline__ float minx32(float v) {
  int a = (((int)threadIdx.x ^ 32) & 63) << 2;
  return fminf(v, __int_as_float(__builtin_amdgcn_ds_bpermute(a, __float_as_int(v))));
}
#endif

// ---------------------------------------------------------------------------
// Kernel 3: producer/consumer scan.  2 waves, 1 workgroup.
//   wave1 (producer): sllr2 -> LDS ring halves (8 blocks each), ping-pong.
//   wave0 (consumer): the r7-verified chain (identical masks/operands/order):
//     per step { t = prob + r ; prob = pair-min over mask }
//     block masks: g0: 8,16,32,4 | g1: 2,1,8,16 | g2: 32,4,2,1
//   Boundary rows: regs pb[H] -> flushed (float4 x2, transposed trajT[l][blk])
//   at the START of the next half so stores retire before the barrier drain.
// ---------------------------------------------------------------------------
__global__ __launch_bounds__(128) void scan_kernel(
    const float4* __restrict__ sllr2, float* __restrict__ trajT,
    float* __restrict__ state, int nblocks, int rem, int gstride, int first) {
  __shared__ float4 ring[2][H][3][64];
  const int tid = threadIdx.x;
  const int l = tid & 63;
  const int nh = nblocks / H;

#define GROUP(qv, M1, M2, M3, M4)                   \
  do { float t_;                                    \
    t_ = prob + (qv).x; prob = M1(t_);              \
    t_ = prob + (qv).y; prob = M2(t_);              \
    t_ = prob + (qv).z; prob = M3(t_);              \
    t_ = prob + (qv).w; prob = M4(t_);              \
  } while (0)

  if (tid >= 64) {
    // ---------------- producer wave ----------------
    if (nh > 0) {
      const float4* src = sllr2 + l;
#pragma unroll
      for (int i = 0; i < H; ++i) {
        ring[0][i][0][l] = src[(size_t)i * 192];
        ring[0][i][1][l] = src[(size_t)i * 192 + 64];
        ring[0][i][2][l] = src[(size_t)i * 192 + 128];
      }
    }
    __syncthreads();
    for (int h = 0; h < nh; ++h) {
      if (h + 1 < nh) {
        const float4* src = sllr2 + (size_t)(h + 1) * H * 192 + l;
        const int hb = (h + 1) & 1;
#pragma unroll
        for (int i = 0; i < H; ++i) {
          ring[hb][i][0][l] = src[(size_t)i * 192];
          ring[hb][i][1][l] = src[(size_t)i * 192 + 64];
          ring[hb][i][2][l] = src[(size_t)i * 192 + 128];
        }
      }
      __syncthreads();
    }
  } else {
    // ---------------- consumer wave ----------------
    float prob = first ? 0.0f : state[l];
    float pb[H];
#pragma unroll
    for (int i = 0; i < H; ++i) pb[i] = 0.0f;
    float* tp = trajT + (size_t)l * gstride;

    __syncthreads();   // matches producer prefill barrier
    for (int h = 0; h < nh; ++h) {
      if (h > 0) {  // flush previous half's boundary rows (stores retire during this half)
        float* d = tp + (size_t)(h - 1) * H;
        *(float4*)d       = make_float4(pb[0], pb[1], pb[2], pb[3]);
        *(float4*)(d + 4) = make_float4(pb[4], pb[5], pb[6], pb[7]);
      }
      const int hb = h & 1;
      float4 cq0 = ring[hb][0][0][l], cq1 = ring[hb][0][1][l], cq2 = ring[hb][0][2][l];
#pragma unroll
      for (int i = 0; i < H; ++i) {
        float4 n0, n1, n2;
        if (i + 1 < H) { n0 = ring[hb][i+1][0][l]; n1 = ring[hb][i+1][1][l]; n2 = ring[hb][i+1][2][l]; }
        else           { n0 = cq0; n1 = cq1; n2 = cq2; }
        pb[i] = prob;
        GROUP(cq0, amin8,  minx16, minx32, amin4);
        GROUP(cq1, amin2,  amin1,  amin8,  minx16);
        GROUP(cq2, minx32, amin4,  amin2,  amin1);
        cq0 = n0; cq1 = n1; cq2 = n2;
      }
      __syncthreads();
    }
    if (nh > 0) {  // flush last half
      float* d = tp + (size_t)(nh - 1) * H;
      *(float4*)d       = make_float4(pb[0], pb[1], pb[2], pb[3]);
      *(float4*)(d + 4) = make_float4(pb[4], pb[5], pb[6], pb[7]);
    }
    // leftover whole blocks (< H): direct global reads (r7 path)
    for (int b2 = nh * H; b2 < nblocks; ++b2) {
      const float4* nb = sllr2 + (size_t)b2 * 192 + l;
      float4 q0 = nb[0], q1 = nb[64], q2 = nb[128];
      tp[b2] = prob;
      GROUP(q0, amin8,  minx16, minx32, amin4);
      GROUP(q1, amin2,  amin1,  amin8,  minx16);
      GROUP(q2, minx32, amin4,  amin2,  amin1);
    }
    if (rem > 0) {  // tail groups (<3): store boundary, run phase0 (+phase1)
      const float4* nb = sllr2 + (size_t)nblocks * 192 + l;
      tp[nblocks] = prob;
      float4 q0 = nb[0];
      GROUP(q0, amin8, minx16, minx32, amin4);
      if (rem > 1) {
        float4 q1 = nb[64];
        GROUP(q1, amin2, amin1, amin8, minx16);
      }
    }
    state[l] = prob;
  }
#undef GROUP
}

// ---------------------------------------------------------------------------
// Kernel 4: per-t bit.  Un-permute block-boundary row with sigma0^-1 (r5-r7
// verified formula) from transposed trajT[lane][block], rebuild r = t%12 local
// trellis steps (exact reference op order), strict-< argmin parity.
// ---------------------------------------------------------------------------
__global__ __launch_bounds__(256) void bits_kernel(
    const float* __restrict__ trajT, const float* __restrict__ llrnat,
    float* __restrict__ out, int n, int gstride) {
  int t = blockIdx.x * 256 + threadIdx.x;
  if (t >= n) return;
  int bk = t / 12, r = t % 12;
  float cur[32];
#pragma unroll
  for (int j = 0; j < 32; ++j) {
    int j0 = j & 1, j1 = (j >> 1) & 1, j2 = (j >> 2) & 1, j3 = (j >> 3) & 1, j4 = (j >> 4) & 1;
    int lm = 8 * j0 + 16 * j1 + 32 * j2 + 4 * j3 + 2 * j4;
    cur[j] = trajT[(size_t)lm * gstride + bk];
  }
  for (int q = 0; q < r; ++q) {
    const float* L = llrnat + (size_t)(12 * bk + q) * 64;
    float nw[32];
#pragma unroll
    for (int j = 0; j < 32; ++j) {
      nw[j] = fminf(cur[(2 * j) & 31] + L[2 * j], cur[(2 * j + 1) & 31] + L[2 * j + 1]);
    }
#pragma unroll
    for (int j = 0; j < 32; ++j) cur[j] = nw[j];
  }
  float best = cur[0]; int bi = 0;
#pragma unroll
  for (int i = 1; i < 32; ++i) {
    if (cur[i] < best) { best = cur[i]; bi = i; }
  }
  out[t] = (float)(bi & 1);
}

// ---------------------------------------------------------------------------
extern "C" void kernel_launch(void* const* d_in, const int* in_sizes, int n_in,
                              void* d_out, int out_size, void* d_ws, size_t ws_size,
                              hipStream_t stream) {
  const float* rx = (const float*)d_in[0];
  const float* W1 = (const float*)d_in[1];
  const float* b1 = (const float*)d_in[2];
  const float* W2 = (const float*)d_in[3];
  const float* b2 = (const float*)d_in[4];
  const float* W3 = (const float*)d_in[5];
  const float* b3 = (const float*)d_in[6];
  float* out = (float*)d_out;

#define GSTRIDE(c) ((((c) / 12 + 2) + 3) & ~3)
  // ws: llrnat(c*64) + sllr2((ceil(c/12)+2)*768) + trajT(64*gstride) + state
#define NEED(c) ((size_t)(c) * 64 * 4 \
               + ((size_t)(((c) + 11) / 12) + 2) * 768 * 4 \
               + (size_t)64 * GSTRIDE(c) * 4 + 1024)
  int CH = -1;
  if (NEED(T_TOTAL) <= ws_size) CH = T_TOTAL;
  if (CH < 0) {
    for (int m = T_TOTAL / 3072; m >= 1; --m) {
      int c = 3072 * m;
      if (NEED(c) <= ws_size) { CH = c; break; }
    }
  }
  if (CH < 0) CH = 3072;
#undef NEED
  const int GSMAX = GSTRIDE(CH);

  float*  llrnat = (float*)d_ws;
  float4* sllr2  = (float4*)(llrnat + (size_t)CH * 64);
  float*  trajT  = (float*)(sllr2 + ((size_t)((CH + 11) / 12) + 2) * 192);
  float*  state  = trajT + (size_t)64 * GSMAX;

  for (int t0 = 0; t0 < T_TOTAL; t0 += CH) {
    int c = (T_TOTAL - t0 < CH) ? (T_TOTAL - t0) : CH;  // multiple of 1024
    int npb = (c + 11) / 12;
    int nblocks = c / 12;               // whole 12-step blocks
    int rem = c / 4 - 3 * nblocks;      // leftover 4-step groups (0..2)
    mlp_kernel <<<c / 256, 256, 0, stream>>>(rx + t0, W1, b1, W2, b2, W3, b3, llrnat, c);
    pack_kernel<<<(npb * 192 + 255) / 256, 256, 0, stream>>>(llrnat, sllr2, c, npb);
    scan_kernel<<<1, 128, 0, stream>>>(sllr2, trajT, state, nblocks, rem, GSMAX, (t0 == 0) ? 1 : 0);
    bits_kernel<<<c / 256, 256, 0, stream>>>(trajT, llrnat, out + t0, c, GSMAX);
  }
}